// Round 8
// baseline (305.817 us; speedup 1.0000x reference)
//
#include <hip/hip_runtime.h>

// ---------------------------------------------------------------------------
// SelfAttention (GN -> QKV 1x1 -> softmax(QK^T/16)V -> proj 1x1 + residual)
// B=8, C=256, GROUPS=32, H=W=64 -> T=4096. fp32 in/out.
//
// R12 = R11 (R7 attn + fused prep) with K DOUBLE-BUFFERED in attn:
//   - k_lds8[2]: K(st+1) issues at TOP of iter (full-iter prefetch, was
//     half) into kbuf^1; post-S barrier no longer protects k_lds8.
//   - Barriers 4 -> 3: TOP [vmcnt(8)+bar] | S | exp2/P |
//     MID [vmcnt(4) lgkmcnt(0)+bar] (V landed + P visible, merged) | PV |
//     BOT [lgkmcnt(0)+bar] | issue V(st+1).
//   - LDS 74 KB -> still 2 blocks/CU.  R8/R9/R10 lessons kept: 2 blocks/CU,
//     KVBLK=64, no bpermute on the LDS pipe.
// ---------------------------------------------------------------------------

typedef unsigned short u16;
typedef unsigned char u8;
typedef __attribute__((ext_vector_type(8))) short short8;   // 8 bf16 = 4 VGPR
typedef __attribute__((ext_vector_type(4))) float f32x4;    // 16x16 C/D

#define MFMA16(a, b, c) __builtin_amdgcn_mfma_f32_16x16x32_bf16((a), (b), (c), 0, 0, 0)
#define MFMA16F8(a, b, c) __builtin_amdgcn_mfma_f32_16x16x32_fp8_fp8((a), (b), (c), 0, 0, 0)

#define GLL16(g, l)                                                            \
  __builtin_amdgcn_global_load_lds(                                            \
      (const __attribute__((address_space(1))) void*)(g),                      \
      (__attribute__((address_space(3))) void*)(l), 16, 0, 0)

// pipeline barriers: never wait vmcnt(0) in the loop
#define BAR_VM8()      asm volatile("s_waitcnt vmcnt(8)\n\ts_barrier" ::: "memory")
#define BAR_VM4_LGKM() asm volatile("s_waitcnt vmcnt(4) lgkmcnt(0)\n\ts_barrier" ::: "memory")
#define BAR_LGKM()     asm volatile("s_waitcnt lgkmcnt(0)\n\ts_barrier" ::: "memory")

#define CVT_PK_BF16(dst, lo, hi)                                               \
  asm("v_cvt_pk_bf16_f32 %0, %1, %2" : "=v"(dst) : "v"(lo), "v"(hi))

__device__ __forceinline__ u16 f2bf(float f) {  // RNE fp32 -> bf16 bits
  union { float f; unsigned u; } v; v.f = f;
  unsigned u = v.u;
  return (u16)((u + 0x7FFFu + ((u >> 16) & 1u)) >> 16);
}

__device__ __forceinline__ u8 f2fp8(float f) {  // fp32 -> OCP e4m3 byte
  int p = __builtin_amdgcn_cvt_pk_fp8_f32(f, f, 0, false);
  return (u8)(p & 0xff);
}

// ---------------------------------------------------------------------------
// 0) prep: blocks 0-255 = weights fp32->bf16 (wq|wk|wv|wp -> 4 x 65536);
//    blocks 256-511 = GroupNorm for one (b,g): stats then normalize +
//    transpose 8ch x 4096t -> h_t (B,T,C) bf16 (phase-2 re-read L2-hot).
__global__ __launch_bounds__(256) void prep(
    const float* __restrict__ x,
    const float* __restrict__ gamma, const float* __restrict__ beta,
    const float* __restrict__ wq, const float* __restrict__ wk,
    const float* __restrict__ wv, const float* __restrict__ wp,
    u16* __restrict__ wb, u16* __restrict__ h_t) {
  const int bid = blockIdx.x, tid = threadIdx.x;
  if (bid < 256) {  // weight conversion (block-uniform branch)
    const int m = bid >> 6;
    const float* s = (m == 0) ? wq : (m == 1) ? wk : (m == 2) ? wv : wp;
    const int i = ((bid & 63) * 256 + tid) * 4;
    float4 v = *(const float4*)(s + i);
    u16* d = wb + m * 65536 + i;
    d[0] = f2bf(v.x); d[1] = f2bf(v.y); d[2] = f2bf(v.z); d[3] = f2bf(v.w);
    return;
  }
  const int gid = bid - 256;          // (b,g)
  const int b = gid >> 5, g = gid & 31;
  const float* p = x + (long)gid * 32768;

  // ---- phase 1: stats over the contiguous 32768-float chunk
  float s = 0.f, ss = 0.f;
  #pragma unroll 8
  for (int i = 0; i < 32; ++i) {
    float4 v = *(const float4*)(p + tid * 4 + i * 1024);
    s  += v.x + v.y + v.z + v.w;
    ss += v.x * v.x + v.y * v.y + v.z * v.z + v.w * v.w;
  }
  for (int off = 32; off; off >>= 1) {
    s  += __shfl_down(s, off);
    ss += __shfl_down(ss, off);
  }
  __shared__ float2 red[4];
  __shared__ float2 stat;
  if ((tid & 63) == 0) red[tid >> 6] = make_float2(s, ss);
  __syncthreads();
  if (tid == 0) {
    float S  = red[0].x + red[1].x + red[2].x + red[3].x;
    float SS = red[0].y + red[1].y + red[2].y + red[3].y;
    float mean = S * (1.f / 32768.f);
    float var  = SS * (1.f / 32768.f) - mean * mean;
    stat = make_float2(mean, rsqrtf(var + 1e-5f));
  }
  __syncthreads();
  const float mean = stat.x, rstd = stat.y;

  // ---- phase 2: normalize + transpose (reads are L2-hot)
  __shared__ float tile[8][257];
  const int cr = tid >> 5;            // read channel row 0..7
  const int c_g = g * 8;
  const float gm = gamma[c_g + cr] * rstd;
  const float bt = beta[c_g + cr] - mean * gm;
  const float* xc = x + ((long)(b * 256 + c_g + cr) * 4096);
  u16* hb = h_t + ((long)b * 4096) * 256 + c_g;

  for (int ch = 0; ch < 16; ++ch) {
    const int t0 = ch * 256;
    {
      const int tj = (tid & 31) * 8;
      float4 v0 = *(const float4*)(xc + t0 + tj);
      float4 v1 = *(const float4*)(xc + t0 + tj + 4);
      tile[cr][tj + 0] = v0.x * gm + bt;
      tile[cr][tj + 1] = v0.y * gm + bt;
      tile[cr][tj + 2] = v0.z * gm + bt;
      tile[cr][tj + 3] = v0.w * gm + bt;
      tile[cr][tj + 4] = v1.x * gm + bt;
      tile[cr][tj + 5] = v1.y * gm + bt;
      tile[cr][tj + 6] = v1.z * gm + bt;
      tile[cr][tj + 7] = v1.w * gm + bt;
    }
    __syncthreads();
    {
      uint4 o;
      CVT_PK_BF16(o.x, tile[0][tid], tile[1][tid]);
      CVT_PK_BF16(o.y, tile[2][tid], tile[3][tid]);
      CVT_PK_BF16(o.z, tile[4][tid], tile[5][tid]);
      CVT_PK_BF16(o.w, tile[6][tid], tile[7][tid]);
      *(uint4*)(hb + (long)(t0 + tid) * 256) = o;
    }
    __syncthreads();
  }
}

// ---------------------------------------------------------------------------
// gemm_bt (128x128 tile, BK=32, 4 waves, XOR granule swizzle).
template <bool ROW_BIAS, bool RESID>
__global__ __launch_bounds__(256, 2) void gemm_bt(
    const u16* __restrict__ A, long strideAz, const u16* __restrict__ B,
    long strideBz, const float* __restrict__ bias, float scale,
    u16* __restrict__ outb, float* __restrict__ outf,
    const float* __restrict__ resid, long strideOz, int N) {
  __shared__ u16 a_lds[128 * 32];
  __shared__ u16 b_lds[128 * 32];
  const int tid = threadIdx.x, w = tid >> 6, l = tid & 63;
  const int l15 = l & 15, l4 = l >> 4;
  const int bz = blockIdx.z;
  A += bz * strideAz;
  B += bz * strideBz;
  const long obase = (long)bz * strideOz;
  const int m0 = blockIdx.y * 128, n0 = blockIdx.x * 128;
  const int wm = (w >> 1) * 64, wn = (w & 1) * 64;

  f32x4 acc[4][4];
  #pragma unroll
  for (int i = 0; i < 4; ++i)
    #pragma unroll
    for (int j = 0; j < 4; ++j) acc[i][j] = (f32x4)0.f;

  for (int kt = 0; kt < 8; ++kt) {
    const int k0 = kt * 32;
    __syncthreads();
    #pragma unroll
    for (int j = 0; j < 2; ++j) {
      const int r0 = (w * 2 + j) * 16;
      const int row = r0 + (l >> 2);
      const int sg = (l & 3) ^ (row & 3);
      GLL16(A + (long)(m0 + row) * 256 + k0 + sg * 8, a_lds + r0 * 32);
      GLL16(B + (long)(n0 + row) * 256 + k0 + sg * 8, b_lds + r0 * 32);
    }
    __syncthreads();
    short8 af[4], bf[4];
    #pragma unroll
    for (int t = 0; t < 4; ++t) {
      const int ra = wm + t * 16 + l15;
      af[t] = *(const short8*)(a_lds + ra * 32 + ((l4 ^ (ra & 3)) * 8));
      const int rb = wn + t * 16 + l15;
      bf[t] = *(const short8*)(b_lds + rb * 32 + ((l4 ^ (rb & 3)) * 8));
    }
    #pragma unroll
    for (int mt = 0; mt < 4; ++mt)
      #pragma unroll
      for (int nt = 0; nt < 4; ++nt) acc[mt][nt] = MFMA16(af[mt], bf[nt], acc[mt][nt]);
  }

  if (!ROW_BIAS) {
    float bv[4];
    #pragma unroll
    for (int nt = 0; nt < 4; ++nt) bv[nt] = bias[n0 + wn + nt * 16 + l15];
    #pragma unroll
    for (int mt = 0; mt < 4; ++mt)
      #pragma unroll
      for (int nt = 0; nt < 4; ++nt)
        #pragma unroll
        for (int r = 0; r < 4; ++r) {
          const int row = m0 + wm + mt * 16 + l4 * 4 + r;
          const int col = n0 + wn + nt * 16 + l15;
          outb[obase + (long)row * N + col] = f2bf((acc[mt][nt][r] + bv[nt]) * scale);
        }
  } else {
    float bm[4][4];
    #pragma unroll
    for (int mt = 0; mt < 4; ++mt)
      #pragma unroll
      for (int r = 0; r < 4; ++r) bm[mt][r] = bias[m0 + wm + mt * 16 + l4 * 4 + r];
    #pragma unroll
    for (int mt = 0; mt < 4; ++mt)
      #pragma unroll
      for (int nt = 0; nt < 4; ++nt)
        #pragma unroll
        for (int r = 0; r < 4; ++r) {
          const int row = m0 + wm + mt * 16 + l4 * 4 + r;
          const int col = n0 + wn + nt * 16 + l15;
          const long idx = obase + (long)row * N + col;
          float v = acc[mt][nt][r] + bm[mt][r];
          if (RESID) outf[idx] = v + resid[idx];
          else       outb[idx] = f2bf(v);
        }
  }
}

// ---------------------------------------------------------------------------
// merged Q+K projection -> fp8 e4m3 outputs.  Q scaled 0.25; K scaled
// 0.25*log2(e) so Qs8.Ks8 = score/16 * log2(e) and softmax = exp2 directly.
// cols 0-255 -> Qs8 (bias bq), 256-511 -> Ks8.
__global__ __launch_bounds__(256, 2) void gemm_qk(
    const u16* __restrict__ A, const u16* __restrict__ Bw,
    const float* __restrict__ bq, const float* __restrict__ bk,
    u8* __restrict__ Qs8, u8* __restrict__ Ks8) {
  __shared__ u16 a_lds[128 * 32];
  __shared__ u16 b_lds[128 * 32];
  const int tid = threadIdx.x, w = tid >> 6, l = tid & 63;
  const int l15 = l & 15, l4 = l >> 4;
  const int m0 = blockIdx.y * 128, n0 = blockIdx.x * 128;
  const int wm = (w >> 1) * 64, wn = (w & 1) * 64;

  f32x4 acc[4][4];
  #pragma unroll
  for (int i = 0; i < 4; ++i)
    #pragma unroll
    for (int j = 0; j < 4; ++j) acc[i][j] = (f32x4)0.f;

  for (int kt = 0; kt < 8; ++kt) {
    const int k0 = kt * 32;
    __syncthreads();
    #pragma unroll
    for (int j = 0; j < 2; ++j) {
      const int r0 = (w * 2 + j) * 16;
      const int row = r0 + (l >> 2);
      const int sg = (l & 3) ^ (row & 3);
      GLL16(A + (long)(m0 + row) * 256 + k0 + sg * 8, a_lds + r0 * 32);
      GLL16(Bw + (long)(n0 + row) * 256 + k0 + sg * 8, b_lds + r0 * 32);
    }
    __syncthreads();
    short8 af[4], bf[4];
    #pragma unroll
    for (int t = 0; t < 4; ++t) {
      const int ra = wm + t * 16 + l15;
      af[t] = *(const short8*)(a_lds + ra * 32 + ((l4 ^ (ra & 3)) * 8));
      const int rb = wn + t * 16 + l15;
      bf[t] = *(const short8*)(b_lds + rb * 32 + ((l4 ^ (rb & 3)) * 8));
    }
    #pragma unroll
    for (int mt = 0; mt < 4; ++mt)
      #pragma unroll
      for (int nt = 0; nt < 4; ++nt) acc[mt][nt] = MFMA16(af[mt], bf[nt], acc[mt][nt]);
  }

  const bool isQ = n0 < 256;
  u8* out = isQ ? Qs8 : Ks8;
  const float* bias = isQ ? bq : bk;
  // K carries log2(e): 0.25 * 1.4426950408889634
  const float osc = isQ ? 0.25f : 0.36067376022224085f;
  const int nc0 = n0 & 255;
  float bv[4];
  #pragma unroll
  for (int nt = 0; nt < 4; ++nt) bv[nt] = bias[nc0 + wn + nt * 16 + l15];
  #pragma unroll
  for (int mt = 0; mt < 4; ++mt)
    #pragma unroll
    for (int nt = 0; nt < 4; ++nt)
      #pragma unroll
      for (int r = 0; r < 4; ++r) {
        const int row = m0 + wm + mt * 16 + l4 * 4 + r;
        const int col = nc0 + wn + nt * 16 + l15;
        out[(long)row * 256 + col] = f2fp8((acc[mt][nt][r] + bv[nt]) * osc);
      }
}

// ---------------------------------------------------------------------------
// attention R12: R7 quadrant structure + K double-buffer, 3 barriers/iter.
// Wave w: S^T s in [ws0,+32) ws0=(w&1)*32, q in [wq0,+32) wq0=(w>>1)*32.
// PV: q in [wq0,+32) x c in [(w&1)*128,+128).
// k_lds8[2]: 64 s x 256 B fp8, 16B-granule XOR-16 swizzle.
// Pipeline: TOP [vm8] (K(st) landed) -> issue K(st+1)->kbuf^1 -> S ->
// exp2/P -> MID [vm4 lgkm0] (V(st) landed + P visible) -> PV ->
// BOT [lgkm0] -> issue V(st+1).  K = 4 GLLs (full-iter dist), V = 8 GLLs.
__global__ __launch_bounds__(256, 2) void attn_kernel(
    const u8* __restrict__ Qs8, const u8* __restrict__ Ks8,
    const u16* __restrict__ Vt, u16* __restrict__ Z) {
  __shared__ u8  k_lds8[2][16384];  // 2 x 16 KiB (double-buffered)
  __shared__ u16 v_lds[16384];      // 256 x 64 bf16 (granule-swizzled), 32 KiB
  __shared__ u16 p_lds[64 * 72];    // [q][s] bf16, pad 8 -> 9 KiB
  __shared__ float l_red[256];      // [wave][q] rowsum partials -> inv totals

  const int tid = threadIdx.x, w = tid >> 6, l = tid & 63;
  const int l15 = l & 15, l4 = l >> 4;
  const int bid = blockIdx.x;
  const int batch = bid & 7;   // bid%8: one batch per XCD if XCD = bid%8
  const int qt = bid >> 3;
  const int ws0 = (w & 1) * 32, wq0 = (w >> 1) * 32, wcolO = (w & 1) * 128;
  const long qrow_base = (long)batch * 4096 + qt * 64;

  const u8*  kbase = Ks8 + (long)batch * 4096 * 256;
  const u16* vbase = Vt + (long)batch * 256 * 4096;

  // Q fragments (B-operand of S^T): rows wq0..+31, fp8, 32 VGPR.
  long qf[2][8];
  {
    const u8* qp = Qs8 + (qrow_base + wq0) * 256;
    #pragma unroll
    for (int qt2 = 0; qt2 < 2; ++qt2)
      #pragma unroll
      for (int ks = 0; ks < 8; ++ks)
        qf[qt2][ks] = *(const long*)(qp + (qt2 * 16 + l15) * 256 + ks * 32 + l4 * 8);
  }

  // V staging addresses (j-invariant swizzle)
  const int cvv = 8 * w + (l >> 3);
  const int sgv = (l & 7) ^ (cvv & 7);

  f32x4 o_acc[2][8];
  #pragma unroll
  for (int mt = 0; mt < 2; ++mt)
    #pragma unroll
    for (int nt = 0; nt < 8; ++nt) o_acc[mt][nt] = (f32x4)0.f;
  float rs2[2] = {0.f, 0.f};

  // prologue: issue K(0) -> kbuf[0] [4 GLL] then V(0) [8 GLL]
  #pragma unroll
  for (int j = 0; j < 4; ++j) {
    const int r0 = (j * 4 + w) * 4;
    const int row = r0 + (l >> 4);
    const int g = (l & 15) ^ (row & 15);
    GLL16(kbase + (long)row * 256 + g * 16, k_lds8[0] + r0 * 256);
  }
  #pragma unroll
  for (int j = 0; j < 8; ++j) {
    const int c0 = (j * 4 + w) * 8;
    GLL16(vbase + (long)(c0 + (l >> 3)) * 4096 + sgv * 8, v_lds + c0 * 64);
  }

  for (int st = 0; st < 64; ++st) {
    const int buf = st & 1;
    const int snn = ((st + 1) & 63) * 64;  // next tile (wrap at 63: harmless)

    // TOP: drain own K(st) 4 (oldest of 12) -> K landed block-wide.
    BAR_VM8();

    // issue K(st+1) -> kbuf^1 (last read in S of st-1; two barriers clear)
    #pragma unroll
    for (int j = 0; j < 4; ++j) {
      const int r0 = (j * 4 + w) * 4;
      const int row = r0 + (l >> 4);
      const int g = (l & 15) ^ (row & 15);
      GLL16(kbase + (long)(snn + row) * 256 + g * 16, k_lds8[buf ^ 1] + r0 * 256);
    }

    // S^T quadrant: A = K[s][k] fp8 (m = s), B = qf (n = q)
    f32x4 sacc[2][2];
    #pragma unroll
    for (int i = 0; i < 2; ++i)
      #pragma unroll
      for (int j = 0; j < 2; ++j) sacc[i][j] = (f32x4)0.f;
    __builtin_amdgcn_s_setprio(1);
    #pragma unroll
    for (int ks = 0; ks < 8; ++ks) {
      long kf[2];
      #pragma unroll
      for (int st2 = 0; st2 < 2; ++st2) {
        const int row = ws0 + st2 * 16 + l15;
        const int g = (ks * 2 + (l4 >> 1)) ^ l15;  // row&15 == l15
        kf[st2] = *(const long*)(k_lds8[buf] + row * 256 + g * 16 + (l4 & 1) * 8);
      }
      #pragma unroll
      for (int st2 = 0; st2 < 2; ++st2)
        #pragma unroll
        for (int qt2 = 0; qt2 < 2; ++qt2)
          sacc[st2][qt2] = MFMA16F8(kf[st2], qf[qt2][ks], sacc[st2][qt2]);
    }
    __builtin_amdgcn_s_setprio(0);

    // exp2 + rowsum + P write: lane holds s = ws0+st2*16+l4*4+r,
    // q = wq0+qt2*16+l15.  sacc is already score*log2(e).
    #pragma unroll
    for (int st2 = 0; st2 < 2; ++st2)
      #pragma unroll
      for (int qt2 = 0; qt2 < 2; ++qt2) {
        float e0 = __builtin_exp2f(sacc[st2][qt2][0]);
        float e1 = __builtin_exp2f(sacc[st2][qt2][1]);
        float e2 = __builtin_exp2f(sacc[st2][qt2][2]);
        float e3 = __builtin_exp2f(sacc[st2][qt2][3]);
        rs2[qt2] += (e0 + e1) + (e2 + e3);
        unsigned pw0, pw1;
        CVT_PK_BF16(pw0, e0, e1);
        CVT_PK_BF16(pw1, e2, e3);
        *(uint2*)(p_lds + (wq0 + qt2 * 16 + l15) * 72 + ws0 + st2 * 16 + l4 * 4) =
            make_uint2(pw0, pw1);
      }

    // MID: drain own V(st) 8 (oldest; K(st+1) 4 stay in flight) + all own
    // LDS ops (P write) -> barrier: V landed + P visible block-wide.
    BAR_VM4_LGKM();

    // O += P V
    __builtin_amdgcn_s_setprio(1);
    #pragma unroll
    for (int ks2 = 0; ks2 < 2; ++ks2) {
      short8 pa[2];
      #pragma unroll
      for (int mt = 0; mt < 2; ++mt)
        pa[mt] = *(const short8*)(p_lds + (wq0 + mt * 16 + l15) * 72 + ks2 * 32 + l4 * 8);
      #pragma unroll
      for (int nt = 0; nt < 8; ++nt) {
        const int c = wcolO + nt * 16 + l15;
        const int gv = (ks2 * 4 + l4) ^ (c & 7);
        short8 vb = *(const short8*)(v_lds + c * 64 + gv * 8);
        #pragma unroll
        for (int mt = 0; mt < 2; ++mt) o_acc[mt][nt] = MFMA16(pa[mt], vb, o_acc[mt][nt]);
      }
    }
    __builtin_amdgcn_s_setprio(0);

    // BOT: all waves past v_lds / p_lds reads.
    BAR_LGKM();

    // issue V(st+1): drains during S(st+1)
    #pragma unroll
    for (int j = 0; j < 8; ++j) {
      const int c0 = (j * 4 + w) * 8;
      GLL16(vbase + (long)(c0 + (l >> 3)) * 4096 + snn + sgv * 8, v_lds + c0 * 64);
    }
  }

  // rowsums: lane (qt2,l15) holds partial over its 8 s; reduce over l4, then
  // across the wave pair (same wq0, different ws0) via l_red.
  #pragma unroll
  for (int qt2 = 0; qt2 < 2; ++qt2) {
    float v = rs2[qt2];
    v += __shfl_xor(v, 16);
    v += __shfl_xor(v, 32);
    if (l4 == 0) l_red[w * 64 + wq0 + qt2 * 16 + l15] = v;
  }
  __syncthreads();
  if (tid < 64) {
    const int w0 = (tid >> 5) * 2;  // q<32: waves 0+1; q>=32: waves 2+3
    float t = l_red[w0 * 64 + tid] + l_red[(w0 + 1) * 64 + tid];
    l_red[tid] = 1.f / t;
  }
  __syncthreads();

  // normalize + store Z (B,T,C) bf16
  #pragma unroll
  for (int mt = 0; mt < 2; ++mt) {
    float inv[4];
    #pragma unroll
    for (int r = 0; r < 4; ++r) inv[r] = l_red[wq0 + mt * 16 + l4 * 4 + r];
    #pragma unroll
    for (int nt = 0; nt < 8; ++nt) {
      const int col = wcolO + nt * 16 + l15;
      #pragma unroll
      for (int r = 0; r < 4; ++r) {
        const long row = qrow_base + wq0 + mt * 16 + l4 * 4 + r;
        Z[row * 256 + col] = f2bf(o_acc[mt][nt][r] * inv[r]);
      }
    }
  }
}

// ---------------------------------------------------------------------------
extern "C" void kernel_launch(void* const* d_in, const int* in_sizes, int n_in,
                              void* d_out, int out_size, void* d_ws, size_t ws_size,
                              hipStream_t stream) {
  (void)in_sizes; (void)n_in; (void)out_size; (void)ws_size;
  const float* x     = (const float*)d_in[0];
  const float* gamma = (const float*)d_in[1];
  const float* beta  = (const float*)d_in[2];
  const float* wq    = (const float*)d_in[3];
  const float* bq    = (const float*)d_in[4];
  const float* wk    = (const float*)d_in[5];
  const float* bk    = (const float*)d_in[6];
  const float* wv    = (const float*)d_in[7];
  const float* bv    = (const float*)d_in[8];
  const float* wp    = (const float*)d_in[9];
  const float* bp    = (const float*)d_in[10];
  float* out = (float*)d_out;

  char* ws = (char*)d_ws;
  u16*    wb    = (u16*)(ws);                  // 4 x 65536 bf16 (wq|wk|wv|wp)
  u16*    h_t   = (u16*)(ws + 526336);         // (B,T,C) bf16, 16 MiB
  u8*     Qs8   = (u8*)(ws + 17303552);        // (B,T,C) fp8 (q/4), 8 MiB
  u8*     Ks8   = (u8*)(ws + 25692160);        // (B,T,C) fp8 (k*log2e/4), 8 MiB
  u16*    Vt    = (u16*)(ws + 34080768);       // (B,C,T) bf16, 16 MiB
  u16*    Zb    = (u16*)(ws + 50857984);       // (B,T,C) bf16, 16 MiB

  // fused: weights bf16 + GroupNorm stats/normalize/transpose
  prep<<<dim3(512), dim3(256), 0, stream>>>(x, gamma, beta, wq, wk, wv, wp,
                                            wb, h_t);

  const long sB = 4096L * 256L, sO = 256L * 4096L;
  // Q+K merged: (32768x256) x (512x256)^T -> fp8, one pass over h_t
  gemm_qk<<<dim3(4, 256), dim3(256), 0, stream>>>(h_t, wb, bq, bk, Qs8, Ks8);
  // V^T per batch: (256x256) x (4096x256)^T -> (B,C,T)
  gemm_bt<true, false><<<dim3(32, 2, 8), dim3(256), 0, stream>>>(
      wb + 2 * 65536, 0L, h_t, sB, bv, 1.0f, Vt, nullptr, nullptr, sO, 4096);

  attn_kernel<<<dim3(512), dim3(256), 0, stream>>>(Qs8, Ks8, Vt, Zb);

  // proj per batch + bias + residual -> fp32 out (B,C,T)
  gemm_bt<true, true><<<dim3(32, 2, 8), dim3(256), 0, stream>>>(
      wb + 3 * 65536, 0L, Zb, sB, bp, 1.0f, nullptr, out, x, sO, 4096);
}

// Round 9
// 289.683 us; speedup vs baseline: 1.0557x; 1.0557x over previous
//
#include <hip/hip_runtime.h>

// ---------------------------------------------------------------------------
// SelfAttention (GN -> QKV 1x1 -> softmax(QK^T/16)V -> proj 1x1 + residual)
// B=8, C=256, GROUPS=32, H=W=64 -> T=4096. fp32 in/out.
//
// R13 = R11 (R7 attn schedule + fused prep; best measured) with ONE change:
//   disjoint-c PV: wcolO = w*64 (was (w&1)*128).  Each wave computes all
//   64 q rows x its private 64-c quarter.  vb reads 16->8 b128 (kills the
//   wave-pair duplicate V reads); pa reads 4->8 b128; net -4 b128/wave/iter
//   off the LDS pipe (~60% busy, the most-loaded resource).
//   Schedule, S phase, barriers, staging: byte-identical to R11.
//   Dead theories (measured): barrier-count reduction (R8/R9/R10/R12 all
//   regressed vs R7's 4-barrier split-wait schedule).
// ---------------------------------------------------------------------------

typedef unsigned short u16;
typedef unsigned char u8;
typedef __attribute__((ext_vector_type(8))) short short8;   // 8 bf16 = 4 VGPR
typedef __attribute__((ext_vector_type(4))) float f32x4;    // 16x16 C/D

#define MFMA16(a, b, c) __builtin_amdgcn_mfma_f32_16x16x32_bf16((a), (b), (c), 0, 0, 0)
#define MFMA16F8(a, b, c) __builtin_amdgcn_mfma_f32_16x16x32_fp8_fp8((a), (b), (c), 0, 0, 0)

#define GLL16(g, l)                                                            \
  __builtin_amdgcn_global_load_lds(                                            \
      (const __attribute__((address_space(1))) void*)(g),                      \
      (__attribute__((address_space(3))) void*)(l), 16, 0, 0)

// pipeline barriers: never wait vmcnt(0); K staging = 4 GLLs, V = 8 GLLs
#define BAR_VM8()  asm volatile("s_waitcnt vmcnt(8)\n\ts_barrier" ::: "memory")
#define BAR_VM4()  asm volatile("s_waitcnt vmcnt(4)\n\ts_barrier" ::: "memory")
#define BAR_LGKM() asm volatile("s_waitcnt lgkmcnt(0)\n\ts_barrier" ::: "memory")

#define CVT_PK_BF16(dst, lo, hi)                                               \
  asm("v_cvt_pk_bf16_f32 %0, %1, %2" : "=v"(dst) : "v"(lo), "v"(hi))

__device__ __forceinline__ u16 f2bf(float f) {  // RNE fp32 -> bf16 bits
  union { float f; unsigned u; } v; v.f = f;
  unsigned u = v.u;
  return (u16)((u + 0x7FFFu + ((u >> 16) & 1u)) >> 16);
}

__device__ __forceinline__ u8 f2fp8(float f) {  // fp32 -> OCP e4m3 byte
  int p = __builtin_amdgcn_cvt_pk_fp8_f32(f, f, 0, false);
  return (u8)(p & 0xff);
}

// ---------------------------------------------------------------------------
// 0) prep: blocks 0-255 = weights fp32->bf16 (wq|wk|wv|wp -> 4 x 65536);
//    blocks 256-511 = GroupNorm for one (b,g): stats then normalize +
//    transpose 8ch x 4096t -> h_t (B,T,C) bf16 (phase-2 re-read L2-hot).
__global__ __launch_bounds__(256) void prep(
    const float* __restrict__ x,
    const float* __restrict__ gamma, const float* __restrict__ beta,
    const float* __restrict__ wq, const float* __restrict__ wk,
    const float* __restrict__ wv, const float* __restrict__ wp,
    u16* __restrict__ wb, u16* __restrict__ h_t) {
  const int bid = blockIdx.x, tid = threadIdx.x;
  if (bid < 256) {  // weight conversion (block-uniform branch)
    const int m = bid >> 6;
    const float* s = (m == 0) ? wq : (m == 1) ? wk : (m == 2) ? wv : wp;
    const int i = ((bid & 63) * 256 + tid) * 4;
    float4 v = *(const float4*)(s + i);
    u16* d = wb + m * 65536 + i;
    d[0] = f2bf(v.x); d[1] = f2bf(v.y); d[2] = f2bf(v.z); d[3] = f2bf(v.w);
    return;
  }
  const int gid = bid - 256;          // (b,g)
  const int b = gid >> 5, g = gid & 31;
  const float* p = x + (long)gid * 32768;

  // ---- phase 1: stats over the contiguous 32768-float chunk
  float s = 0.f, ss = 0.f;
  #pragma unroll 8
  for (int i = 0; i < 32; ++i) {
    float4 v = *(const float4*)(p + tid * 4 + i * 1024);
    s  += v.x + v.y + v.z + v.w;
    ss += v.x * v.x + v.y * v.y + v.z * v.z + v.w * v.w;
  }
  for (int off = 32; off; off >>= 1) {
    s  += __shfl_down(s, off);
    ss += __shfl_down(ss, off);
  }
  __shared__ float2 red[4];
  __shared__ float2 stat;
  if ((tid & 63) == 0) red[tid >> 6] = make_float2(s, ss);
  __syncthreads();
  if (tid == 0) {
    float S  = red[0].x + red[1].x + red[2].x + red[3].x;
    float SS = red[0].y + red[1].y + red[2].y + red[3].y;
    float mean = S * (1.f / 32768.f);
    float var  = SS * (1.f / 32768.f) - mean * mean;
    stat = make_float2(mean, rsqrtf(var + 1e-5f));
  }
  __syncthreads();
  const float mean = stat.x, rstd = stat.y;

  // ---- phase 2: normalize + transpose (reads are L2-hot)
  __shared__ float tile[8][257];
  const int cr = tid >> 5;            // read channel row 0..7
  const int c_g = g * 8;
  const float gm = gamma[c_g + cr] * rstd;
  const float bt = beta[c_g + cr] - mean * gm;
  const float* xc = x + ((long)(b * 256 + c_g + cr) * 4096);
  u16* hb = h_t + ((long)b * 4096) * 256 + c_g;

  for (int ch = 0; ch < 16; ++ch) {
    const int t0 = ch * 256;
    {
      const int tj = (tid & 31) * 8;
      float4 v0 = *(const float4*)(xc + t0 + tj);
      float4 v1 = *(const float4*)(xc + t0 + tj + 4);
      tile[cr][tj + 0] = v0.x * gm + bt;
      tile[cr][tj + 1] = v0.y * gm + bt;
      tile[cr][tj + 2] = v0.z * gm + bt;
      tile[cr][tj + 3] = v0.w * gm + bt;
      tile[cr][tj + 4] = v1.x * gm + bt;
      tile[cr][tj + 5] = v1.y * gm + bt;
      tile[cr][tj + 6] = v1.z * gm + bt;
      tile[cr][tj + 7] = v1.w * gm + bt;
    }
    __syncthreads();
    {
      uint4 o;
      CVT_PK_BF16(o.x, tile[0][tid], tile[1][tid]);
      CVT_PK_BF16(o.y, tile[2][tid], tile[3][tid]);
      CVT_PK_BF16(o.z, tile[4][tid], tile[5][tid]);
      CVT_PK_BF16(o.w, tile[6][tid], tile[7][tid]);
      *(uint4*)(hb + (long)(t0 + tid) * 256) = o;
    }
    __syncthreads();
  }
}

// ---------------------------------------------------------------------------
// gemm_bt (128x128 tile, BK=32, 4 waves, XOR granule swizzle).
template <bool ROW_BIAS, bool RESID>
__global__ __launch_bounds__(256, 2) void gemm_bt(
    const u16* __restrict__ A, long strideAz, const u16* __restrict__ B,
    long strideBz, const float* __restrict__ bias, float scale,
    u16* __restrict__ outb, float* __restrict__ outf,
    const float* __restrict__ resid, long strideOz, int N) {
  __shared__ u16 a_lds[128 * 32];
  __shared__ u16 b_lds[128 * 32];
  const int tid = threadIdx.x, w = tid >> 6, l = tid & 63;
  const int l15 = l & 15, l4 = l >> 4;
  const int bz = blockIdx.z;
  A += bz * strideAz;
  B += bz * strideBz;
  const long obase = (long)bz * strideOz;
  const int m0 = blockIdx.y * 128, n0 = blockIdx.x * 128;
  const int wm = (w >> 1) * 64, wn = (w & 1) * 64;

  f32x4 acc[4][4];
  #pragma unroll
  for (int i = 0; i < 4; ++i)
    #pragma unroll
    for (int j = 0; j < 4; ++j) acc[i][j] = (f32x4)0.f;

  for (int kt = 0; kt < 8; ++kt) {
    const int k0 = kt * 32;
    __syncthreads();
    #pragma unroll
    for (int j = 0; j < 2; ++j) {
      const int r0 = (w * 2 + j) * 16;
      const int row = r0 + (l >> 2);
      const int sg = (l & 3) ^ (row & 3);
      GLL16(A + (long)(m0 + row) * 256 + k0 + sg * 8, a_lds + r0 * 32);
      GLL16(B + (long)(n0 + row) * 256 + k0 + sg * 8, b_lds + r0 * 32);
    }
    __syncthreads();
    short8 af[4], bf[4];
    #pragma unroll
    for (int t = 0; t < 4; ++t) {
      const int ra = wm + t * 16 + l15;
      af[t] = *(const short8*)(a_lds + ra * 32 + ((l4 ^ (ra & 3)) * 8));
      const int rb = wn + t * 16 + l15;
      bf[t] = *(const short8*)(b_lds + rb * 32 + ((l4 ^ (rb & 3)) * 8));
    }
    #pragma unroll
    for (int mt = 0; mt < 4; ++mt)
      #pragma unroll
      for (int nt = 0; nt < 4; ++nt) acc[mt][nt] = MFMA16(af[mt], bf[nt], acc[mt][nt]);
  }

  if (!ROW_BIAS) {
    float bv[4];
    #pragma unroll
    for (int nt = 0; nt < 4; ++nt) bv[nt] = bias[n0 + wn + nt * 16 + l15];
    #pragma unroll
    for (int mt = 0; mt < 4; ++mt)
      #pragma unroll
      for (int nt = 0; nt < 4; ++nt)
        #pragma unroll
        for (int r = 0; r < 4; ++r) {
          const int row = m0 + wm + mt * 16 + l4 * 4 + r;
          const int col = n0 + wn + nt * 16 + l15;
          outb[obase + (long)row * N + col] = f2bf((acc[mt][nt][r] + bv[nt]) * scale);
        }
  } else {
    float bm[4][4];
    #pragma unroll
    for (int mt = 0; mt < 4; ++mt)
      #pragma unroll
      for (int r = 0; r < 4; ++r) bm[mt][r] = bias[m0 + wm + mt * 16 + l4 * 4 + r];
    #pragma unroll
    for (int mt = 0; mt < 4; ++mt)
      #pragma unroll
      for (int nt = 0; nt < 4; ++nt)
        #pragma unroll
        for (int r = 0; r < 4; ++r) {
          const int row = m0 + wm + mt * 16 + l4 * 4 + r;
          const int col = n0 + wn + nt * 16 + l15;
          const long idx = obase + (long)row * N + col;
          float v = acc[mt][nt][r] + bm[mt][r];
          if (RESID) outf[idx] = v + resid[idx];
          else       outb[idx] = f2bf(v);
        }
  }
}

// ---------------------------------------------------------------------------
// merged Q+K projection -> fp8 e4m3 outputs.  Q scaled 0.25; K scaled
// 0.25*log2(e) so Qs8.Ks8 = score/16 * log2(e) and softmax = exp2 directly.
// cols 0-255 -> Qs8 (bias bq), 256-511 -> Ks8.
__global__ __launch_bounds__(256, 2) void gemm_qk(
    const u16* __restrict__ A, const u16* __restrict__ Bw,
    const float* __restrict__ bq, const float* __restrict__ bk,
    u8* __restrict__ Qs8, u8* __restrict__ Ks8) {
  __shared__ u16 a_lds[128 * 32];
  __shared__ u16 b_lds[128 * 32];
  const int tid = threadIdx.x, w = tid >> 6, l = tid & 63;
  const int l15 = l & 15, l4 = l >> 4;
  const int m0 = blockIdx.y * 128, n0 = blockIdx.x * 128;
  const int wm = (w >> 1) * 64, wn = (w & 1) * 64;

  f32x4 acc[4][4];
  #pragma unroll
  for (int i = 0; i < 4; ++i)
    #pragma unroll
    for (int j = 0; j < 4; ++j) acc[i][j] = (f32x4)0.f;

  for (int kt = 0; kt < 8; ++kt) {
    const int k0 = kt * 32;
    __syncthreads();
    #pragma unroll
    for (int j = 0; j < 2; ++j) {
      const int r0 = (w * 2 + j) * 16;
      const int row = r0 + (l >> 2);
      const int sg = (l & 3) ^ (row & 3);
      GLL16(A + (long)(m0 + row) * 256 + k0 + sg * 8, a_lds + r0 * 32);
      GLL16(Bw + (long)(n0 + row) * 256 + k0 + sg * 8, b_lds + r0 * 32);
    }
    __syncthreads();
    short8 af[4], bf[4];
    #pragma unroll
    for (int t = 0; t < 4; ++t) {
      const int ra = wm + t * 16 + l15;
      af[t] = *(const short8*)(a_lds + ra * 32 + ((l4 ^ (ra & 3)) * 8));
      const int rb = wn + t * 16 + l15;
      bf[t] = *(const short8*)(b_lds + rb * 32 + ((l4 ^ (rb & 3)) * 8));
    }
    #pragma unroll
    for (int mt = 0; mt < 4; ++mt)
      #pragma unroll
      for (int nt = 0; nt < 4; ++nt) acc[mt][nt] = MFMA16(af[mt], bf[nt], acc[mt][nt]);
  }

  const bool isQ = n0 < 256;
  u8* out = isQ ? Qs8 : Ks8;
  const float* bias = isQ ? bq : bk;
  // K carries log2(e): 0.25 * 1.4426950408889634
  const float osc = isQ ? 0.25f : 0.36067376022224085f;
  const int nc0 = n0 & 255;
  float bv[4];
  #pragma unroll
  for (int nt = 0; nt < 4; ++nt) bv[nt] = bias[nc0 + wn + nt * 16 + l15];
  #pragma unroll
  for (int mt = 0; mt < 4; ++mt)
    #pragma unroll
    for (int nt = 0; nt < 4; ++nt)
      #pragma unroll
      for (int r = 0; r < 4; ++r) {
        const int row = m0 + wm + mt * 16 + l4 * 4 + r;
        const int col = nc0 + wn + nt * 16 + l15;
        out[(long)row * 256 + col] = f2fp8((acc[mt][nt][r] + bv[nt]) * osc);
      }
}

// ---------------------------------------------------------------------------
// attention R13: R7/R11 schedule; PV disjoint-c (wcolO = w*64).
// Wave w: S^T s in [ws0,+32) ws0=(w&1)*32, q in [wq0,+32) wq0=(w>>1)*32.
// PV: ALL 64 q rows x c in [w*64,+64) (disjoint across waves -> no
// duplicate vb reads; pa read for all 4 q-quadrants from p_lds).
// k_lds8: 64 s-rows x 256 B fp8, 16B-granule XOR-16 swizzle.
// Pipeline: [vm8] S -> exp2 -> P(cvt_pk, b64) -> [lgkm] issue K+1 ->
// [vm4] PV -> [lgkm] issue V+1.  K = 4 GLLs, V = 8 GLLs.
__global__ __launch_bounds__(256, 2) void attn_kernel(
    const u8* __restrict__ Qs8, const u8* __restrict__ Ks8,
    const u16* __restrict__ Vt, u16* __restrict__ Z) {
  __shared__ u8  k_lds8[16384];   // 64 x 256 B (granule-swizzled), 16 KiB
  __shared__ u16 v_lds[16384];    // 256 x 64 bf16 (granule-swizzled), 32 KiB
  __shared__ u16 p_lds[64 * 72];  // [q][s] bf16, pad 8 -> 9 KiB
  __shared__ float l_red[256];    // [wave][q] rowsum partials -> inv totals

  const int tid = threadIdx.x, w = tid >> 6, l = tid & 63;
  const int l15 = l & 15, l4 = l >> 4;
  const int bid = blockIdx.x;
  const int batch = bid & 7;   // bid%8: one batch per XCD if XCD = bid%8
  const int qt = bid >> 3;
  const int ws0 = (w & 1) * 32, wq0 = (w >> 1) * 32;
  const int wcolO = w * 64;    // R13: private c-quarter per wave
  const long qrow_base = (long)batch * 4096 + qt * 64;

  const u8*  kbase = Ks8 + (long)batch * 4096 * 256;
  const u16* vbase = Vt + (long)batch * 256 * 4096;

  // Q fragments (B-operand of S^T): rows wq0..+31, fp8, 32 VGPR.
  long qf[2][8];
  {
    const u8* qp = Qs8 + (qrow_base + wq0) * 256;
    #pragma unroll
    for (int qt2 = 0; qt2 < 2; ++qt2)
      #pragma unroll
      for (int ks = 0; ks < 8; ++ks)
        qf[qt2][ks] = *(const long*)(qp + (qt2 * 16 + l15) * 256 + ks * 32 + l4 * 8);
  }

  // V staging addresses (j-invariant swizzle)
  const int cvv = 8 * w + (l >> 3);
  const int sgv = (l & 7) ^ (cvv & 7);

  f32x4 o_acc[4][4];   // [q-quadrant][c-subtile], 64 VGPR (same as R11)
  #pragma unroll
  for (int mt = 0; mt < 4; ++mt)
    #pragma unroll
    for (int nt = 0; nt < 4; ++nt) o_acc[mt][nt] = (f32x4)0.f;
  float rs2[2] = {0.f, 0.f};

  // prologue: issue K(0) [4 GLL] then V(0) [8 GLL] -> 12 outstanding
  #pragma unroll
  for (int j = 0; j < 4; ++j) {
    const int r0 = (j * 4 + w) * 4;
    const int row = r0 + (l >> 4);
    const int g = (l & 15) ^ (row & 15);
    GLL16(kbase + (long)row * 256 + g * 16, k_lds8 + r0 * 256);
  }
  #pragma unroll
  for (int j = 0; j < 8; ++j) {
    const int c0 = (j * 4 + w) * 8;
    GLL16(vbase + (long)(c0 + (l >> 3)) * 4096 + sgv * 8, v_lds + c0 * 64);
  }

  for (int st = 0; st < 64; ++st) {
    const int snn = ((st + 1) & 63) * 64;  // next tile (wrap at 63: harmless)

    BAR_VM8();  // K(st) landed block-wide (V(st) 8 still in flight)

    // S^T quadrant: A = K[s][k] fp8 (m = s), B = qf (n = q)
    f32x4 sacc[2][2];
    #pragma unroll
    for (int i = 0; i < 2; ++i)
      #pragma unroll
      for (int j = 0; j < 2; ++j) sacc[i][j] = (f32x4)0.f;
    __builtin_amdgcn_s_setprio(1);
    #pragma unroll
    for (int ks = 0; ks < 8; ++ks) {
      long kf[2];
      #pragma unroll
      for (int st2 = 0; st2 < 2; ++st2) {
        const int row = ws0 + st2 * 16 + l15;
        const int g = (ks * 2 + (l4 >> 1)) ^ l15;  // row&15 == l15
        kf[st2] = *(const long*)(k_lds8 + row * 256 + g * 16 + (l4 & 1) * 8);
      }
      #pragma unroll
      for (int st2 = 0; st2 < 2; ++st2)
        #pragma unroll
        for (int qt2 = 0; qt2 < 2; ++qt2)
          sacc[st2][qt2] = MFMA16F8(kf[st2], qf[qt2][ks], sacc[st2][qt2]);
    }
    __builtin_amdgcn_s_setprio(0);

    // exp2 + rowsum + P write: lane holds s = ws0+st2*16+l4*4+r,
    // q = wq0+qt2*16+l15.  sacc is already score*log2(e).
    #pragma unroll
    for (int st2 = 0; st2 < 2; ++st2)
      #pragma unroll
      for (int qt2 = 0; qt2 < 2; ++qt2) {
        float e0 = __builtin_exp2f(sacc[st2][qt2][0]);
        float e1 = __builtin_exp2f(sacc[st2][qt2][1]);
        float e2 = __builtin_exp2f(sacc[st2][qt2][2]);
        float e3 = __builtin_exp2f(sacc[st2][qt2][3]);
        rs2[qt2] += (e0 + e1) + (e2 + e3);
        unsigned pw0, pw1;
        CVT_PK_BF16(pw0, e0, e1);
        CVT_PK_BF16(pw1, e2, e3);
        *(uint2*)(p_lds + (wq0 + qt2 * 16 + l15) * 72 + ws0 + st2 * 16 + l4 * 4) =
            make_uint2(pw0, pw1);
      }

    BAR_LGKM();  // P visible; all waves past their k_lds8 reads

    // issue K(st+1): drains during PV(st)
    #pragma unroll
    for (int j = 0; j < 4; ++j) {
      const int r0 = (j * 4 + w) * 4;
      const int row = r0 + (l >> 4);
      const int g = (l & 15) ^ (row & 15);
      GLL16(kbase + (long)(snn + row) * 256 + g * 16, k_lds8 + r0 * 256);
    }

    BAR_VM4();  // V(st) landed block-wide (K(st+1) 4 still in flight)

    // O += P V : all 4 q-quadrants x private c-quarter (disjoint vb)
    __builtin_amdgcn_s_setprio(1);
    #pragma unroll
    for (int ks2 = 0; ks2 < 2; ++ks2) {
      short8 pa[4];
      #pragma unroll
      for (int mt = 0; mt < 4; ++mt)
        pa[mt] = *(const short8*)(p_lds + (mt * 16 + l15) * 72 + ks2 * 32 + l4 * 8);
      #pragma unroll
      for (int nt = 0; nt < 4; ++nt) {
        const int c = wcolO + nt * 16 + l15;
        const int gv = (ks2 * 4 + l4) ^ (c & 7);
        short8 vb = *(const short8*)(v_lds + c * 64 + gv * 8);
        #pragma unroll
        for (int mt = 0; mt < 4; ++mt) o_acc[mt][nt] = MFMA16(pa[mt], vb, o_acc[mt][nt]);
      }
    }
    __builtin_amdgcn_s_setprio(0);

    BAR_LGKM();  // all waves past v_lds / p_lds reads

    // issue V(st+1): drains during S(st+1)
    #pragma unroll
    for (int j = 0; j < 8; ++j) {
      const int c0 = (j * 4 + w) * 8;
      GLL16(vbase + (long)(c0 + (l >> 3)) * 4096 + snn + sgv * 8, v_lds + c0 * 64);
    }
  }

  // rowsums: lane (qt2,l15) holds partial over its 8 s; reduce over l4, then
  // across the wave pair (same wq0, different ws0) via l_red.
  #pragma unroll
  for (int qt2 = 0; qt2 < 2; ++qt2) {
    float v = rs2[qt2];
    v += __shfl_xor(v, 16);
    v += __shfl_xor(v, 32);
    if (l4 == 0) l_red[w * 64 + wq0 + qt2 * 16 + l15] = v;
  }
  __syncthreads();
  if (tid < 64) {
    const int w0 = (tid >> 5) * 2;  // q<32: waves 0+1; q>=32: waves 2+3
    float t = l_red[w0 * 64 + tid] + l_red[(w0 + 1) * 64 + tid];
    l_red[tid] = 1.f / t;
  }
  __syncthreads();

  // normalize + store Z (B,T,C) bf16: all 64 q rows x private c-quarter
  #pragma unroll
  for (int mt = 0; mt < 4; ++mt) {
    float inv[4];
    #pragma unroll
    for (int r = 0; r < 4; ++r) inv[r] = l_red[mt * 16 + l4 * 4 + r];
    #pragma unroll
    for (int nt = 0; nt < 4; ++nt) {
      const int col = wcolO + nt * 16 + l15;
      #pragma unroll
      for (int r = 0; r < 4; ++r) {
        const long row = qrow_base + mt * 16 + l4 * 4 + r;
        Z[row * 256 + col] = f2bf(o_acc[mt][nt][r] * inv[r]);
      }
    }
  }
}

// ---------------------------------------------------------------------------
extern "C" void kernel_launch(void* const* d_in, const int* in_sizes, int n_in,
                              void* d_out, int out_size, void* d_ws, size_t ws_size,
                              hipStream_t stream) {
  (void)in_sizes; (void)n_in; (void)out_size; (void)ws_size;
  const float* x     = (const float*)d_in[0];
  const float* gamma = (const float*)d_in[1];
  const float* beta  = (const float*)d_in[2];
  const float* wq    = (const float*)d_in[3];
  const float* bq    = (const float*)d_in[4];
  const float* wk    = (const float*)d_in[5];
  const float* bk    = (const float*)d_in[6];
  const float* wv    = (const float*)d_in[7];
  const float* bv    = (const float*)d_in[8];
  const float* wp    = (const float*)d_in[9];
  const float* bp    = (const float*)d_in[10];
  float* out = (float*)d_out;

  char* ws = (char*)d_ws;
  u16*    wb    = (u16*)(ws);                  // 4 x 65536 bf16 (wq|wk|wv|wp)
  u16*    h_t   = (u16*)(ws + 526336);         // (B,T,C) bf16, 16 MiB
  u8*     Qs8   = (u8*)(ws + 17303552);        // (B,T,C) fp8 (q/4), 8 MiB
  u8*     Ks8   = (u8*)(ws + 25692160);        // (B,T,C) fp8 (k*log2e/4), 8 MiB
  u16*    Vt    = (u16*)(ws + 34080768);       // (B,C,T) bf16, 16 MiB
  u16*    Zb    = (u16*)(ws + 50857984);       // (B,T,C) bf16, 16 MiB

  // fused: weights bf16 + GroupNorm stats/normalize/transpose
  prep<<<dim3(512), dim3(256), 0, stream>>>(x, gamma, beta, wq, wk, wv, wp,
                                            wb, h_t);

  const long sB = 4096L * 256L, sO = 256L * 4096L;
  // Q+K merged: (32768x256) x (512x256)^T -> fp8, one pass over h_t
  gemm_qk<<<dim3(4, 256), dim3(256), 0, stream>>>(h_t, wb, bq, bk, Qs8, Ks8);
  // V^T per batch: (256x256) x (4096x256)^T -> (B,C,T)
  gemm_bt<true, false><<<dim3(32, 2, 8), dim3(256), 0, stream>>>(
      wb + 2 * 65536, 0L, h_t, sB, bv, 1.0f, Vt, nullptr, nullptr, sO, 4096);

  attn_kernel<<<dim3(512), dim3(256), 0, stream>>>(Qs8, Ks8, Vt, Zb);

  // proj per batch + bias + residual -> fp32 out (B,C,T)
  gemm_bt<true, true><<<dim3(32, 2, 8), dim3(256), 0, stream>>>(
      wb + 3 * 65536, 0L, Zb, sB, bp, 1.0f, nullptr, out, x, sO, 4096);
}